// Round 10
// baseline (716.976 us; speedup 1.0000x reference)
//
#include <hip/hip_runtime.h>
#include <stdint.h>

// fused: out = l2norm(relu(x@W1+b1) @ W2 + b2)
// x:[N,64] f32, W1:[64,64], b1:[64], W2:[64,128], b2:[128], out:[N,128] f32
//
// Swapped-operand MFMA: A = W^T frag, B = x/h frag -> D[col=sample][row=dim].
// Lane owns 4 consecutive output dims per acc quad -> dwordx4 stores, 2-shfl reduce.
//
// R7: launch_bounds(256,4) forced 64 VGPR -> spills (+900MB traffic, 500us).
// R9: relaxed bound, ping-pong prefetch -> ~230us (bench 700). Suspect: ping-pong
//     uA/uB (32 VGPR) + lambdas raised pressure; occupancy < 4 waves/SIMD.
// R10: single-buffer prefetch (convert u->xf, THEN overwrite u with next tile),
//      consecutive tiles per block (streaming locality), nontemporal out stores.

typedef __attribute__((ext_vector_type(8))) short short8;   // 8 bf16 (MFMA A/B frag)
typedef __attribute__((ext_vector_type(4))) float f32x4;    // MFMA C/D frag

#define TILES_PER_BLOCK 5

__device__ __forceinline__ ushort f2bf(float f) {
    union { float f; uint32_t u; } v; v.f = f;
    uint32_t u = v.u;
    u += 0x7fffu + ((u >> 16) & 1u);   // round-to-nearest-even
    return (ushort)(u >> 16);
}
__device__ __forceinline__ uint32_t pack2(float a, float b) {
    return (uint32_t)f2bf(a) | ((uint32_t)f2bf(b) << 16);
}

__global__ __launch_bounds__(256)
void fused_head_kernel(const float* __restrict__ x,
                       const float* __restrict__ W1,
                       const float* __restrict__ b1,
                       const float* __restrict__ W2,
                       const float* __restrict__ b2,
                       float* __restrict__ out,
                       int ntiles)
{
    // stride 72 ushorts = 144 B = 9*16B: rows 16B-aligned, uniform bank spread
    __shared__ ushort w1t[64][72];      // w1t[n][k] = W1[k][n]
    __shared__ ushort w2t[128][72];     // w2t[n][k] = W2[k][n]
    __shared__ ushort htile[4][16][72]; // per-wave: htile[w][sample][k]
    __shared__ __align__(16) float b1s[64];
    __shared__ __align__(16) float b2s[128];

    const int tid  = threadIdx.x;
    const int wave = tid >> 6;
    const int lane = tid & 63;
    const int l16  = lane & 15;   // sample within wave-tile
    const int lq   = lane >> 4;   // 0..3

    const int t0   = blockIdx.x * TILES_PER_BLOCK;
    if (t0 >= ntiles) return;
    const int tcnt = (ntiles - t0 < TILES_PER_BLOCK) ? (ntiles - t0) : TILES_PER_BLOCK;

    // per-thread x base for tile t0 (each tile advances 64 rows = 4096 floats)
    const float* px = x + ((size_t)(t0 * 64 + wave * 16 + l16)) * 64 + lq * 8;

    // ---- prologue: issue tile-0 x loads before weight staging (latency hides) ----
    f32x4 u[4];
    u[0] = *(const f32x4*)px;        u[1] = *(const f32x4*)(px + 4);
    u[2] = *(const f32x4*)(px + 32); u[3] = *(const f32x4*)(px + 36);

    // ---- stage weights + biases (once per block) ----
    for (int idx = tid; idx < 64 * 64; idx += 256) {
        int k = idx >> 6, n = idx & 63;
        w1t[n][k] = f2bf(W1[idx]);
    }
    for (int idx = tid; idx < 64 * 128; idx += 256) {
        int k = idx >> 7, n = idx & 127;
        w2t[n][k] = f2bf(W2[idx]);
    }
    if (tid < 64)  b1s[tid] = b1[tid];
    if (tid < 128) b2s[tid] = b2[tid];
    __syncthreads();

    for (int i = 0; i < tcnt; ++i) {
        const int t = t0 + i;

        // ---- convert current x to B-frags: x[sample=l16][k=32h+8lq+e] ----
        short8 xf[2];
#pragma unroll
        for (int h = 0; h < 2; ++h) {
            short8 v;
            v[0] = (short)f2bf(u[2*h][0]);   v[1] = (short)f2bf(u[2*h][1]);
            v[2] = (short)f2bf(u[2*h][2]);   v[3] = (short)f2bf(u[2*h][3]);
            v[4] = (short)f2bf(u[2*h+1][0]); v[5] = (short)f2bf(u[2*h+1][1]);
            v[6] = (short)f2bf(u[2*h+1][2]); v[7] = (short)f2bf(u[2*h+1][3]);
            xf[h] = v;
        }

        // ---- prefetch next tile's x into u (overwrites AFTER conversion);
        //      the whole compute phase below covers the HBM latency ----
        if (i + 1 < tcnt) {
            const float* p = px + (size_t)(i + 1) * 4096;
            u[0] = *(const f32x4*)p;        u[1] = *(const f32x4*)(p + 4);
            u[2] = *(const f32x4*)(p + 32); u[3] = *(const f32x4*)(p + 36);
        }

        // ---- stage 1: acc1[nt][r] = h_pre[sample=l16][dim=16nt+4lq+r] ----
        f32x4 acc1[4] = {};
#pragma unroll
        for (int h = 0; h < 2; ++h)
#pragma unroll
            for (int nt = 0; nt < 4; ++nt) {
                short8 wf = *(const short8*)&w1t[nt * 16 + l16][h * 32 + lq * 8];
                acc1[nt] = __builtin_amdgcn_mfma_f32_16x16x32_bf16(wf, xf[h], acc1[nt], 0, 0, 0);
            }

        // bias+relu -> htile[wave][own sample row l16][dim] as packed bf16 pairs
#pragma unroll
        for (int nt = 0; nt < 4; ++nt) {
            f32x4 bv = *(const f32x4*)&b1s[nt * 16 + lq * 4];
            float h0 = acc1[nt][0] + bv[0]; h0 = h0 > 0.f ? h0 : 0.f;
            float h1 = acc1[nt][1] + bv[1]; h1 = h1 > 0.f ? h1 : 0.f;
            float h2 = acc1[nt][2] + bv[2]; h2 = h2 > 0.f ? h2 : 0.f;
            float h3 = acc1[nt][3] + bv[3]; h3 = h3 > 0.f ? h3 : 0.f;
            uint32_t* dst = (uint32_t*)&htile[wave][l16][nt * 16 + lq * 4];
            dst[0] = pack2(h0, h1);
            dst[1] = pack2(h2, h3);
        }
        // wave-private buffer, in-order LDS per wave: no barrier needed

        // ---- stage 2: acc2[nt][r] = e[sample=l16][dim=16nt+4lq+r] ----
        f32x4 acc2[8] = {};
#pragma unroll
        for (int h = 0; h < 2; ++h) {
            short8 hf = *(const short8*)&htile[wave][l16][h * 32 + lq * 8];
#pragma unroll
            for (int nt = 0; nt < 8; ++nt) {
                short8 wf = *(const short8*)&w2t[nt * 16 + l16][h * 32 + lq * 8];
                acc2[nt] = __builtin_amdgcn_mfma_f32_16x16x32_bf16(wf, hf, acc2[nt], 0, 0, 0);
            }
        }

        // ---- bias + sum of squares: lane holds 32 dims of sample l16 ----
        float ss = 0.f;
#pragma unroll
        for (int nt = 0; nt < 8; ++nt) {
            f32x4 bv = *(const f32x4*)&b2s[nt * 16 + lq * 4];
#pragma unroll
            for (int r = 0; r < 4; ++r) {
                float e = acc2[nt][r] + bv[r];
                acc2[nt][r] = e;
                ss += e * e;
            }
        }
        // combine the 4 lq-groups holding sample l16 (lanes l16+16*lq)
        ss += __shfl_xor(ss, 16, 64);
        ss += __shfl_xor(ss, 32, 64);
        float sc = ss > 0.f ? rsqrtf(ss) : 0.f;   // zero-norm guard

        // ---- nontemporal coalesced dwordx4 stores: 8 instrs x 1KB/wave ----
        float* po = out + ((size_t)(t * 64 + wave * 16 + l16)) * 128 + lq * 4;
#pragma unroll
        for (int nt = 0; nt < 8; ++nt) {
            f32x4 v;
            v[0] = acc2[nt][0] * sc; v[1] = acc2[nt][1] * sc;
            v[2] = acc2[nt][2] * sc; v[3] = acc2[nt][3] * sc;
            __builtin_nontemporal_store(v, (f32x4*)(po + nt * 16));
        }
    }
}

extern "C" void kernel_launch(void* const* d_in, const int* in_sizes, int n_in,
                              void* d_out, int out_size, void* d_ws, size_t ws_size,
                              hipStream_t stream) {
    const float* x  = (const float*)d_in[0];
    const float* W1 = (const float*)d_in[1];
    const float* b1 = (const float*)d_in[2];
    const float* W2 = (const float*)d_in[3];
    const float* b2 = (const float*)d_in[4];
    float* out = (float*)d_out;

    const int nrows  = in_sizes[0] / 64;                       // 1,000,000
    const int ntiles = nrows / 64;                             // 15625
    const int grid   = (ntiles + TILES_PER_BLOCK - 1) / TILES_PER_BLOCK;  // 3125

    hipLaunchKernelGGL(fused_head_kernel, dim3(grid), dim3(256), 0, stream,
                       x, W1, b1, W2, b2, out, ntiles);
}

// Round 11
// 715.499 us; speedup vs baseline: 1.0021x; 1.0021x over previous
//
#include <hip/hip_runtime.h>
#include <hip/hip_bf16.h>
#include <stdint.h>

// fused: out = l2norm(relu(x@W1+b1) @ W2 + b2)
// x:[N,64] f32, W1:[64,64], b1:[64], W2:[64,128], b2:[128], out:[N,128] f32
//
// Swapped-operand MFMA: A = W^T frag, B = x/h frag -> D[col=sample][row=dim].
// Lane owns 4 consecutive output dims per acc quad -> dwordx4 stores, 2-shfl reduce.
//
// R7:  launch_bounds(256,4) forced 64 VGPR -> spills (+900MB traffic, 500us).
// R9:  relaxed bound -> kernel ~230us (bench 700). R10: single-buffer prefetch,
//      nontemporal stores, 5 consecutive tiles/block -> neutral (~240us).
// R11: persistent blocks (grid=1024, ~15-tile contiguous chunks: prologue paid
//      once, longer DRAM streams), __float2bfloat16 (compiler cvt > manual
//      bit-twiddle, m240), nontemporal x loads (zero-reuse stream).

typedef __attribute__((ext_vector_type(8))) short short8;   // 8 bf16 (MFMA A/B frag)
typedef __attribute__((ext_vector_type(4))) float f32x4;    // MFMA C/D frag

#define GRID_BLOCKS 1024

__device__ __forceinline__ ushort f2bf(float f) {
    __hip_bfloat16 h = __float2bfloat16(f);      // RNE; compiler emits good cvt
    return *reinterpret_cast<ushort*>(&h);
}
__device__ __forceinline__ uint32_t pack2(float a, float b) {
    return (uint32_t)f2bf(a) | ((uint32_t)f2bf(b) << 16);
}

__global__ __launch_bounds__(256)
void fused_head_kernel(const float* __restrict__ x,
                       const float* __restrict__ W1,
                       const float* __restrict__ b1,
                       const float* __restrict__ W2,
                       const float* __restrict__ b2,
                       float* __restrict__ out,
                       int ntiles)
{
    // stride 72 ushorts = 144 B = 9*16B: rows 16B-aligned, uniform bank spread
    __shared__ ushort w1t[64][72];      // w1t[n][k] = W1[k][n]
    __shared__ ushort w2t[128][72];     // w2t[n][k] = W2[k][n]
    __shared__ ushort htile[4][16][72]; // per-wave: htile[w][sample][k]
    __shared__ __align__(16) float b1s[64];
    __shared__ __align__(16) float b2s[128];

    const int tid  = threadIdx.x;
    const int wave = tid >> 6;
    const int lane = tid & 63;
    const int l16  = lane & 15;   // sample within wave-tile
    const int lq   = lane >> 4;   // 0..3

    // persistent contiguous chunk: block b owns tiles [b*nt/G, (b+1)*nt/G)
    const int t0   = (int)(((long long)blockIdx.x * ntiles) / GRID_BLOCKS);
    const int t1   = (int)(((long long)(blockIdx.x + 1) * ntiles) / GRID_BLOCKS);
    const int tcnt = t1 - t0;
    if (tcnt <= 0) return;

    // per-thread x base for tile t0 (each tile advances 64 rows = 4096 floats)
    const float* px = x + ((size_t)(t0 * 64 + wave * 16 + l16)) * 64 + lq * 8;

    // ---- prologue: issue tile-0 x loads before weight staging (latency hides) ----
    f32x4 u[4];
    u[0] = __builtin_nontemporal_load((const f32x4*)px);
    u[1] = __builtin_nontemporal_load((const f32x4*)(px + 4));
    u[2] = __builtin_nontemporal_load((const f32x4*)(px + 32));
    u[3] = __builtin_nontemporal_load((const f32x4*)(px + 36));

    // ---- stage weights + biases (once per block) ----
    for (int idx = tid; idx < 64 * 64; idx += 256) {
        int k = idx >> 6, n = idx & 63;
        w1t[n][k] = f2bf(W1[idx]);
    }
    for (int idx = tid; idx < 64 * 128; idx += 256) {
        int k = idx >> 7, n = idx & 127;
        w2t[n][k] = f2bf(W2[idx]);
    }
    if (tid < 64)  b1s[tid] = b1[tid];
    if (tid < 128) b2s[tid] = b2[tid];
    __syncthreads();

    for (int i = 0; i < tcnt; ++i) {
        const int t = t0 + i;

        // ---- convert current x to B-frags: x[sample=l16][k=32h+8lq+e] ----
        short8 xf[2];
#pragma unroll
        for (int h = 0; h < 2; ++h) {
            short8 v;
            v[0] = (short)f2bf(u[2*h][0]);   v[1] = (short)f2bf(u[2*h][1]);
            v[2] = (short)f2bf(u[2*h][2]);   v[3] = (short)f2bf(u[2*h][3]);
            v[4] = (short)f2bf(u[2*h+1][0]); v[5] = (short)f2bf(u[2*h+1][1]);
            v[6] = (short)f2bf(u[2*h+1][2]); v[7] = (short)f2bf(u[2*h+1][3]);
            xf[h] = v;
        }

        // ---- prefetch next tile's x (overwrites u AFTER conversion);
        //      the compute phase below covers the HBM latency ----
        if (i + 1 < tcnt) {
            const float* p = px + (size_t)(i + 1) * 4096;
            u[0] = __builtin_nontemporal_load((const f32x4*)p);
            u[1] = __builtin_nontemporal_load((const f32x4*)(p + 4));
            u[2] = __builtin_nontemporal_load((const f32x4*)(p + 32));
            u[3] = __builtin_nontemporal_load((const f32x4*)(p + 36));
        }

        // ---- stage 1: acc1[nt][r] = h_pre[sample=l16][dim=16nt+4lq+r] ----
        f32x4 acc1[4] = {};
#pragma unroll
        for (int h = 0; h < 2; ++h)
#pragma unroll
            for (int nt = 0; nt < 4; ++nt) {
                short8 wf = *(const short8*)&w1t[nt * 16 + l16][h * 32 + lq * 8];
                acc1[nt] = __builtin_amdgcn_mfma_f32_16x16x32_bf16(wf, xf[h], acc1[nt], 0, 0, 0);
            }

        // bias+relu -> htile[wave][own sample row l16][dim] as packed bf16 pairs
#pragma unroll
        for (int nt = 0; nt < 4; ++nt) {
            f32x4 bv = *(const f32x4*)&b1s[nt * 16 + lq * 4];
            float h0 = acc1[nt][0] + bv[0]; h0 = h0 > 0.f ? h0 : 0.f;
            float h1 = acc1[nt][1] + bv[1]; h1 = h1 > 0.f ? h1 : 0.f;
            float h2 = acc1[nt][2] + bv[2]; h2 = h2 > 0.f ? h2 : 0.f;
            float h3 = acc1[nt][3] + bv[3]; h3 = h3 > 0.f ? h3 : 0.f;
            uint32_t* dst = (uint32_t*)&htile[wave][l16][nt * 16 + lq * 4];
            dst[0] = pack2(h0, h1);
            dst[1] = pack2(h2, h3);
        }
        // wave-private buffer, in-order LDS per wave: no barrier needed

        // ---- stage 2: acc2[nt][r] = e[sample=l16][dim=16nt+4lq+r] ----
        f32x4 acc2[8] = {};
#pragma unroll
        for (int h = 0; h < 2; ++h) {
            short8 hf = *(const short8*)&htile[wave][l16][h * 32 + lq * 8];
#pragma unroll
            for (int nt = 0; nt < 8; ++nt) {
                short8 wf = *(const short8*)&w2t[nt * 16 + l16][h * 32 + lq * 8];
                acc2[nt] = __builtin_amdgcn_mfma_f32_16x16x32_bf16(wf, hf, acc2[nt], 0, 0, 0);
            }
        }

        // ---- bias + sum of squares: lane holds 32 dims of sample l16 ----
        float ss = 0.f;
#pragma unroll
        for (int nt = 0; nt < 8; ++nt) {
            f32x4 bv = *(const f32x4*)&b2s[nt * 16 + lq * 4];
#pragma unroll
            for (int r = 0; r < 4; ++r) {
                float e = acc2[nt][r] + bv[r];
                acc2[nt][r] = e;
                ss += e * e;
            }
        }
        // combine the 4 lq-groups holding sample l16 (lanes l16+16*lq)
        ss += __shfl_xor(ss, 16, 64);
        ss += __shfl_xor(ss, 32, 64);
        float sc = ss > 0.f ? rsqrtf(ss) : 0.f;   // zero-norm guard

        // ---- nontemporal coalesced dwordx4 stores: 8 instrs x 1KB/wave ----
        float* po = out + ((size_t)(t * 64 + wave * 16 + l16)) * 128 + lq * 4;
#pragma unroll
        for (int nt = 0; nt < 8; ++nt) {
            f32x4 v;
            v[0] = acc2[nt][0] * sc; v[1] = acc2[nt][1] * sc;
            v[2] = acc2[nt][2] * sc; v[3] = acc2[nt][3] * sc;
            __builtin_nontemporal_store(v, (f32x4*)(po + nt * 16));
        }
    }
}

extern "C" void kernel_launch(void* const* d_in, const int* in_sizes, int n_in,
                              void* d_out, int out_size, void* d_ws, size_t ws_size,
                              hipStream_t stream) {
    const float* x  = (const float*)d_in[0];
    const float* W1 = (const float*)d_in[1];
    const float* b1 = (const float*)d_in[2];
    const float* W2 = (const float*)d_in[3];
    const float* b2 = (const float*)d_in[4];
    float* out = (float*)d_out;

    const int nrows  = in_sizes[0] / 64;   // 1,000,000
    const int ntiles = nrows / 64;         // 15625

    hipLaunchKernelGGL(fused_head_kernel, dim3(GRID_BLOCKS), dim3(256), 0, stream,
                       x, W1, b1, W2, b2, out, ntiles);
}